// Round 1
// baseline (138.510 us; speedup 1.0000x reference)
//
#include <hip/hip_runtime.h>
#include <hip/hip_bf16.h>
#include <math.h>

#define TT 4096
#define BB 32
#define HH 512
#define CC 32000
#define NCHUNK 64   // t-chunks (TT/TPC)
#define TPC 64      // t per chunk (4 waves x 16 rows)

// ws layout (float offsets)
#define WS_CTX    0          // 32*512 = 16384 floats (persists k2->k3)
#define WS_LPART  16384      // 2048 floats (k1->k2)
#define WS_BIG    18432      // 2,097,152 floats: ctx_part (k1->k2) then out_part (k3->k4)

// ---------------- k1: fused score + weighted partial sums ------------------
// grid (chunk=64, b=32), block 256 (4 waves). Each wave: 16 rows of t.
// For each row: coalesced 2KB load, dot with align_w (butterfly reduce),
// w = exp(tanh(dot+ab)) (bounded, no max-sub needed), accumulate w*x and w.
__global__ __launch_bounds__(256) void k1_partials(
    const float* __restrict__ dec, const float* __restrict__ aw,
    const float* __restrict__ abp,
    float* __restrict__ ctx_part, float* __restrict__ l_part)
{
  const int chunk = blockIdx.x;
  const int b     = blockIdx.y;
  const int tid   = threadIdx.x;
  const int wv = tid >> 6, ln = tid & 63;
  const float ab = abp[0];
  const float4 aw0 = *(const float4*)(aw + ln*8);
  const float4 aw1 = *(const float4*)(aw + ln*8 + 4);
  float4 c0 = make_float4(0.f,0.f,0.f,0.f), c1 = make_float4(0.f,0.f,0.f,0.f);
  float l = 0.f;
  const int t0 = chunk*TPC + wv*16;
  for (int i = 0; i < 16; ++i) {
    const size_t base = ((size_t)(t0+i)*BB + b)*HH + (size_t)ln*8;
    const float4 x0 = *(const float4*)(dec + base);
    const float4 x1 = *(const float4*)(dec + base + 4);
    float d = x0.x*aw0.x + x0.y*aw0.y + x0.z*aw0.z + x0.w*aw0.w
            + x1.x*aw1.x + x1.y*aw1.y + x1.z*aw1.z + x1.w*aw1.w;
    #pragma unroll
    for (int off = 32; off > 0; off >>= 1) d += __shfl_xor(d, off);
    const float e = tanhf(d + ab);
    const float w = expf(e);
    l += w;
    c0.x = fmaf(w, x0.x, c0.x); c0.y = fmaf(w, x0.y, c0.y);
    c0.z = fmaf(w, x0.z, c0.z); c0.w = fmaf(w, x0.w, c0.w);
    c1.x = fmaf(w, x1.x, c1.x); c1.y = fmaf(w, x1.y, c1.y);
    c1.z = fmaf(w, x1.z, c1.z); c1.w = fmaf(w, x1.w, c1.w);
  }
  __shared__ float s_ctx[4][HH];
  __shared__ float s_l[4];
  *(float4*)&s_ctx[wv][ln*8]     = c0;
  *(float4*)&s_ctx[wv][ln*8 + 4] = c1;
  if (ln == 0) s_l[wv] = l;
  __syncthreads();
  if (tid < 128) {
    const int h = tid * 4;
    float4 a = make_float4(0.f,0.f,0.f,0.f);
    #pragma unroll
    for (int w2 = 0; w2 < 4; ++w2) {
      const float4 v = *(const float4*)&s_ctx[w2][h];
      a.x += v.x; a.y += v.y; a.z += v.z; a.w += v.w;
    }
    const size_t p = (size_t)b*NCHUNK + chunk;
    *(float4*)(ctx_part + p*HH + h) = a;
    if (tid == 0) l_part[p] = s_l[0] + s_l[1] + s_l[2] + s_l[3];
  }
}

// ---------------- k2: combine partials -> normalized context ----------------
__global__ __launch_bounds__(128) void k2_combine(
    const float* __restrict__ ctx_part, const float* __restrict__ l_part,
    float* __restrict__ ctx)
{
  const int b = blockIdx.x;
  const int h = threadIdx.x * 4;
  float L = 0.f;
  for (int p = 0; p < NCHUNK; ++p) L += l_part[b*NCHUNK + p];
  float4 a = make_float4(0.f,0.f,0.f,0.f);
  for (int p = 0; p < NCHUNK; ++p) {
    const float4 v = *(const float4*)(ctx_part + ((size_t)b*NCHUNK + p)*HH + h);
    a.x += v.x; a.y += v.y; a.z += v.z; a.w += v.w;
  }
  const float inv = 1.f / L;
  const float4 r = make_float4(a.x*inv, a.y*inv, a.z*inv, a.w*inv);
  *(float4*)(ctx + b*HH + h) = r;
}

// ---------------- k3: out = ctx @ out_w^T (partials over h-halves) ----------
// thread-per-c; ctx reads are wave-uniform (scalar-load friendly);
// out_w row streamed per-lane via float4 (line reuse across hh keeps HBM = 64MB).
__global__ __launch_bounds__(128) void k3_matmul(
    const float* __restrict__ ctx, const float* __restrict__ ow,
    float* __restrict__ out_part)
{
  const int c = blockIdx.x * 128 + threadIdx.x;
  const int half = blockIdx.y;            // h in [half*256, half*256+256)
  const int h0 = half * 256;
  const float* wrow = ow + (size_t)c * HH + h0;
  const float* cb = ctx + h0;             // uniform across block
  float acc[BB];
  #pragma unroll
  for (int b = 0; b < BB; ++b) acc[b] = 0.f;
  for (int hh = 0; hh < 256; hh += 4) {
    const float4 w4 = *(const float4*)(wrow + hh);
    #pragma unroll
    for (int b = 0; b < BB; ++b) {
      const float4 c4 = *(const float4*)(cb + (size_t)b*HH + hh);
      acc[b] = fmaf(w4.w, c4.w, fmaf(w4.z, c4.z, fmaf(w4.y, c4.y, fmaf(w4.x, c4.x, acc[b]))));
    }
  }
  float* op = out_part + (size_t)half * ((size_t)BB*CC);
  #pragma unroll
  for (int b = 0; b < BB; ++b) op[(size_t)b*CC + c] = acc[b];
}

// ---------------- k4: sum halves + bias -> d_out ---------------------------
__global__ __launch_bounds__(256) void k4_final(
    const float* __restrict__ out_part, const float* __restrict__ ob,
    float* __restrict__ out)
{
  const size_t i = ((size_t)blockIdx.x * 256 + threadIdx.x) * 4;
  const float4 p0 = *(const float4*)(out_part + i);
  const float4 p1 = *(const float4*)(out_part + (size_t)BB*CC + i);
  const int cIdx = (int)(i % CC);
  const float4 b4 = *(const float4*)(ob + cIdx);
  const float4 r = make_float4(p0.x+p1.x+b4.x, p0.y+p1.y+b4.y,
                               p0.z+p1.z+b4.z, p0.w+p1.w+b4.w);
  *(float4*)(out + i) = r;
}

extern "C" void kernel_launch(void* const* d_in, const int* in_sizes, int n_in,
                              void* d_out, int out_size, void* d_ws, size_t ws_size,
                              hipStream_t stream) {
  const float* dec = (const float*)d_in[0];
  const float* aw  = (const float*)d_in[1];
  const float* ab  = (const float*)d_in[2];
  const float* ow  = (const float*)d_in[3];
  const float* ob  = (const float*)d_in[4];
  float* out = (float*)d_out;
  float* ws  = (float*)d_ws;
  float* ctx   = ws + WS_CTX;
  float* lpart = ws + WS_LPART;
  float* big   = ws + WS_BIG;   // ctx_part for k1/k2, reused as out_part for k3/k4

  k1_partials<<<dim3(NCHUNK, BB), 256, 0, stream>>>(dec, aw, ab, big, lpart);
  k2_combine<<<dim3(BB), 128, 0, stream>>>(big, lpart, ctx);
  k3_matmul<<<dim3(CC/128, 2), 128, 0, stream>>>(ctx, ow, big);
  k4_final<<<dim3((BB*CC)/(256*4)), 256, 0, stream>>>(big, ob, out);
}